// Round 17
// baseline (208.581 us; speedup 1.0000x reference)
//
#include <hip/hip_runtime.h>

typedef __attribute__((ext_vector_type(4))) float f32x4;
typedef __attribute__((ext_vector_type(8))) __bf16 bf16x8;
typedef __attribute__((ext_vector_type(4))) __bf16 bf16x4;

#define LOG_2PI 1.8378770664093453f

__device__ __forceinline__ float softplus_f(float x) {
  return fmaxf(x, 0.f) + log1pf(expf(-fabsf(x)));
}

__device__ __forceinline__ void barrier_lds_only() {
  asm volatile("s_waitcnt lgkmcnt(0)\n\ts_barrier" ::: "memory");
}

// ---------------- prep: marks_proj (blocks 0..1023) + zero accs (block 1024)
__global__ void prep_kernel(const float* __restrict__ em,
                            const float* __restrict__ Wp,
                            const float* __restrict__ bp,
                            float* __restrict__ mp,
                            float* __restrict__ accs) {
  const int b = blockIdx.x;
  if (b == 1024) {
    if (threadIdx.x < 8) accs[threadIdx.x] = 0.f;
    return;
  }
  const int d = threadIdx.x;
  float s = bp[d];
  const float* emr = em + b * 128;
#pragma unroll 4
  for (int k = 0; k < 128; ++k) s += emr[k] * Wp[k * 128 + d];
  mp[b * 128 + d] = s;
}

// ---------------- intensity: 96-row tri-tiles, W1 (bf16) in LDS -------------
// 256 blocks x 12 waves = 3072 waves; wave gw owns tri-tiles {gw, gw+3072}
// of 6144 96-row tiles over 589824 rows (rows < 524288: z_traj, timestep =
// row>>6; else z_events row-524288). Per tile: 96 rows -> 24 B-frags (96
// VGPR, architecturally live so the allocator cannot sink them); hidden loop
// reads each swizzled W-frag ONCE and feeds 6 MFMA (1.5x the W-reuse of the
// R9 pair structure -> LDS traffic x0.67, load-phase amortization x1.5).
// b1/W2 consumed post-MFMA from LDS (R15 lesson: not at the chain head).
__global__ __launch_bounds__(768, 3) void intensity15_kernel(
    const float* __restrict__ z_traj, const float* __restrict__ z_ev,
    const float* __restrict__ W1, const float* __restrict__ b1,
    const float* __restrict__ W2, const float* __restrict__ b2,
    const float* __restrict__ base_i, const float* __restrict__ times,
    float* __restrict__ accs) {
  __shared__ __align__(16) __bf16 w1t[512 * 128];  // 128 KB: W1^T, swizzled
  __shared__ __align__(16) float b1L[512];
  __shared__ __align__(16) float w2L[512];
  __shared__ float red[12][4];

  const int tid = threadIdx.x;
  const int wid = tid >> 6, lid = tid & 63;
  const int g = lid >> 4, q = lid & 15;

  // ---- one-time W1^T -> LDS (bf16, col-XOR swizzle), b1/W2 -> LDS ----
  if (tid < 512) {
    const float* wcol = W1 + tid;  // W1[k][tid], row stride 512
    char* wbs = (char*)w1t;
    const int colbase = tid * 256;
    const int sw = (tid & 7) << 4;
#pragma unroll 8
    for (int k = 0; k < 128; k += 2) {
      float a = wcol[(size_t)k * 512];
      float c = wcol[(size_t)(k + 1) * 512];
      union { __bf16 h[2]; unsigned u; } pk;
      pk.h[0] = (__bf16)a;
      pk.h[1] = (__bf16)c;
      *(unsigned*)(wbs + (colbase + ((k * 2) ^ sw))) = pk.u;
    }
    b1L[tid] = b1[tid];
    w2L[tid] = W2[tid];
  }
  const float sbias = b2[0] + base_i[0];
  barrier_lds_only();

  const int gw = blockIdx.x * 12 + wid;
  float integral_loc = 0.f, logsum_loc = 0.f, kls = 0.f;
  const char* wb = (const char*)w1t;
  const int wsw = (q & 7) << 4;

#pragma unroll 1
  for (int t = gw; t < 6144; t += 3072) {
    // ---- load 96 rows -> 24 B-frags (per s-group staging, + kls) ----
    bf16x8 fr[6][4];
#pragma unroll
    for (int s = 0; s < 6; ++s) {
      const int row = t * 96 + s * 16 + q;
      const bool tr = (row < 524288);
      const float* rp =
          (tr ? z_traj + (size_t)row * 128 : z_ev + (size_t)(row - 524288) * 128) +
          g * 8;
      f32x4 ld[4][2];
#pragma unroll
      for (int kf = 0; kf < 4; ++kf) {
        ld[kf][0] = *(const f32x4*)(rp + kf * 32);
        ld[kf][1] = *(const f32x4*)(rp + kf * 32 + 4);
      }
#pragma unroll
      for (int kf = 0; kf < 4; ++kf) {
        f32x4 a0 = ld[kf][0], a1 = ld[kf][1];
        if (tr) {
          kls += a0[0] * a0[0] + a0[1] * a0[1] + a0[2] * a0[2] + a0[3] * a0[3];
          kls += a1[0] * a1[0] + a1[1] * a1[1] + a1[2] * a1[2] + a1[3] * a1[3];
        }
        bf16x8 f;
#pragma unroll
        for (int j = 0; j < 4; ++j) {
          f[j] = (__bf16)a0[j];
          f[4 + j] = (__bf16)a1[j];
        }
        fr[s][kf] = f;
      }
    }

    // ---- hidden loop: 32 c-blocks; each W-frag read feeds 6 MFMA ----
    float ra0 = 0.f, ra1 = 0.f, ra2 = 0.f, ra3 = 0.f, ra4 = 0.f, ra5 = 0.f;
#pragma unroll 1
    for (int c = 0; c < 32; ++c) {
      f32x4 a0 = {}, a1 = {}, a2 = {}, a3 = {}, a4 = {}, a5 = {};
#pragma unroll
      for (int kf = 0; kf < 4; ++kf) {
        bf16x8 wf = *(const bf16x8*)(wb + c * 4096 + q * 256 +
                                     ((kf * 64 + g * 16) ^ wsw));
        a0 = __builtin_amdgcn_mfma_f32_16x16x32_bf16(wf, fr[0][kf], a0, 0, 0, 0);
        a1 = __builtin_amdgcn_mfma_f32_16x16x32_bf16(wf, fr[1][kf], a1, 0, 0, 0);
        a2 = __builtin_amdgcn_mfma_f32_16x16x32_bf16(wf, fr[2][kf], a2, 0, 0, 0);
        a3 = __builtin_amdgcn_mfma_f32_16x16x32_bf16(wf, fr[3][kf], a3, 0, 0, 0);
        a4 = __builtin_amdgcn_mfma_f32_16x16x32_bf16(wf, fr[4][kf], a4, 0, 0, 0);
        a5 = __builtin_amdgcn_mfma_f32_16x16x32_bf16(wf, fr[5][kf], a5, 0, 0, 0);
      }
      f32x4 bb = *(const f32x4*)&b1L[c * 16 + g * 4];
      f32x4 ww = *(const f32x4*)&w2L[c * 16 + g * 4];
#pragma unroll
      for (int ii = 0; ii < 4; ++ii) {
        ra0 += fmaxf(a0[ii] + bb[ii], 0.f) * ww[ii];
        ra1 += fmaxf(a1[ii] + bb[ii], 0.f) * ww[ii];
        ra2 += fmaxf(a2[ii] + bb[ii], 0.f) * ww[ii];
        ra3 += fmaxf(a3[ii] + bb[ii], 0.f) * ww[ii];
        ra4 += fmaxf(a4[ii] + bb[ii], 0.f) * ww[ii];
        ra5 += fmaxf(a5[ii] + bb[ii], 0.f) * ww[ii];
      }
    }
    // combine 4 g-groups -> full 512-col row sums (valid at every lane's q)
    ra0 += __shfl_xor(ra0, 16); ra0 += __shfl_xor(ra0, 32);
    ra1 += __shfl_xor(ra1, 16); ra1 += __shfl_xor(ra1, 32);
    ra2 += __shfl_xor(ra2, 16); ra2 += __shfl_xor(ra2, 32);
    ra3 += __shfl_xor(ra3, 16); ra3 += __shfl_xor(ra3, 32);
    ra4 += __shfl_xor(ra4, 16); ra4 += __shfl_xor(ra4, 32);
    ra5 += __shfl_xor(ra5, 16); ra5 += __shfl_xor(ra5, 32);

    // lane (g,q) finishes row s=g; lanes g<2 also finish s=4+g (96 rows, 1:1)
    {
      const float rs = (g == 0) ? ra0 : (g == 1) ? ra1 : (g == 2) ? ra2 : ra3;
      const int row = t * 96 + g * 16 + q;
      const float lam = softplus_f(rs + sbias);
      if (row < 524288) {
        const int ts = row >> 6;
        integral_loc += lam * (times[ts + 1] - times[ts]) * (1.f / 64.f);
      } else {
        logsum_loc += logf(lam + 1e-8f) * (1.f / 64.f);
      }
    }
    if (g < 2) {
      const float rs = (g == 0) ? ra4 : ra5;
      const int row = t * 96 + (4 + g) * 16 + q;
      const float lam = softplus_f(rs + sbias);
      if (row < 524288) {
        const int ts = row >> 6;
        integral_loc += lam * (times[ts + 1] - times[ts]) * (1.f / 64.f);
      } else {
        logsum_loc += logf(lam + 1e-8f) * (1.f / 64.f);
      }
    }
  }

  // ---- wave reduce 3 accumulators, block reduce, 3 atomics ----
#pragma unroll
  for (int m = 32; m >= 1; m >>= 1) {
    integral_loc += __shfl_xor(integral_loc, m);
    logsum_loc += __shfl_xor(logsum_loc, m);
    kls += __shfl_xor(kls, m);
  }
  if (lid == 0) {
    red[wid][0] = integral_loc;
    red[wid][1] = logsum_loc;
    red[wid][2] = kls;
  }
  __syncthreads();
  if (tid == 0) {
    float I = 0.f, L = 0.f, K = 0.f;
#pragma unroll
    for (int w = 0; w < 12; ++w) {
      I += red[w][0];
      L += red[w][1];
      K += red[w][2];
    }
    atomicAdd(&accs[0], I);
    atomicAdd(&accs[1], L);
    atomicAdd(&accs[3], K);
  }
}

// ---------------- decoder2: 256 blocks x 8 tiles (min weight re-reads) ------
__global__ __launch_bounds__(512, 2) void decoder2_kernel(
    const float* __restrict__ z,
    const float* __restrict__ Wd1, const float* __restrict__ bd1,
    const float* __restrict__ Wd2, const float* __restrict__ bd2,
    const float* __restrict__ mp, float* __restrict__ recon_acc) {
  __shared__ __align__(16) __bf16 zbuf[2][32 * 128];  // 16 KB
  __shared__ __align__(16) __bf16 hbuf[32 * 512];     // 32 KB
  __shared__ float s_part[32][9];
  __shared__ float red[8];

  const int tid = threadIdx.x;
  const int wid = tid >> 6, lid = tid & 63;
  const int g = lid >> 4, q = lid & 15;
  const int cb = wid * 64;
  const int tile0 = blockIdx.x * 8;

  bf16x8 bw1[4][4];
  f32x4 bd1v[4];
#pragma unroll
  for (int cf = 0; cf < 4; ++cf) {
    const int col = cb + cf * 16 + q;
#pragma unroll
    for (int i = 0; i < 4; ++i) bd1v[cf][i] = bd1[cb + cf * 16 + g * 4 + i];
#pragma unroll
    for (int kf = 0; kf < 4; ++kf) {
      bf16x8 f;
#pragma unroll
      for (int j = 0; j < 8; ++j) f[j] = (__bf16)Wd1[(kf * 32 + g * 8 + j) * 512 + col];
      bw1[cf][kf] = f;
    }
  }
  const int dimf = wid * 16 + q;
  bf16x8 bw2[16];
#pragma unroll
  for (int kf2 = 0; kf2 < 16; ++kf2) {
    bf16x8 f;
#pragma unroll
    for (int j = 0; j < 8; ++j) f[j] = (__bf16)Wd2[(kf2 * 32 + g * 8 + j) * 128 + dimf];
    bw2[kf2] = f;
  }
  f32x4 bd2v;
#pragma unroll
  for (int i = 0; i < 4; ++i) bd2v[i] = bd2[wid * 16 + g * 4 + i];

  const int srow = tid >> 4, sk8 = (tid & 15) * 8;
  const int stg_byte = ((srow * 256 + sk8 * 2) ^ ((srow & 7) << 4));
  char* hb = (char*)hbuf;

  float local = 0.f;

  {
    const float* p = z + (size_t)tile0 * 4096 + tid * 8;
    f32x4 r0 = *(const f32x4*)p, r1 = *(const f32x4*)(p + 4);
    bf16x8 v;
#pragma unroll
    for (int j = 0; j < 4; ++j) { v[j] = (__bf16)r0[j]; v[4 + j] = (__bf16)r1[j]; }
    *(bf16x8*)((char*)zbuf[0] + stg_byte) = v;
  }
  f32x4 rA0, rA1, rB0, rB1;
  { const float* p = z + (size_t)(tile0 + 1) * 4096 + tid * 8; rA0 = *(const f32x4*)p; rA1 = *(const f32x4*)(p + 4); }
  { const float* p = z + (size_t)(tile0 + 2) * 4096 + tid * 8; rB0 = *(const f32x4*)p; rB1 = *(const f32x4*)(p + 4); }
  barrier_lds_only();

#define DBODY(T, ZC, RR0, RR1)                                                     \
  do {                                                                             \
    f32x4 acc1[2][4] = {};                                                         \
    char* zc = (char*)zbuf[ZC];                                                    \
    _Pragma("unroll") for (int kf = 0; kf < 4; ++kf) {                             \
      _Pragma("unroll") for (int rf = 0; rf < 2; ++rf) {                           \
        const int row = rf * 16 + q;                                               \
        bf16x8 a = *(const bf16x8*)(zc + ((row * 256 + kf * 64 + g * 16) ^ ((row & 7) << 4))); \
        _Pragma("unroll") for (int cf = 0; cf < 4; ++cf)                           \
          acc1[rf][cf] = __builtin_amdgcn_mfma_f32_16x16x32_bf16(bw1[cf][kf], a, acc1[rf][cf], 0, 0, 0); \
      }                                                                            \
    }                                                                              \
    {                                                                              \
      bf16x8 v;                                                                    \
      _Pragma("unroll") for (int j = 0; j < 4; ++j) { v[j] = (__bf16)RR0[j]; v[4 + j] = (__bf16)RR1[j]; } \
      *(bf16x8*)((char*)zbuf[(ZC) ^ 1] + stg_byte) = v;                            \
    }                                                                              \
    {                                                                              \
      int tl = (T) + 3; if (tl > 7) tl = 7;                                        \
      const float* p = z + (size_t)(tile0 + tl) * 4096 + tid * 8;                  \
      RR0 = *(const f32x4*)p; RR1 = *(const f32x4*)(p + 4);                        \
    }                                                                              \
    _Pragma("unroll") for (int rf = 0; rf < 2; ++rf) {                             \
      const int row = rf * 16 + q;                                                 \
      _Pragma("unroll") for (int cf = 0; cf < 4; ++cf) {                           \
        bf16x4 hv;                                                                 \
        _Pragma("unroll") for (int i = 0; i < 4; ++i)                              \
          hv[i] = (__bf16)fmaxf(acc1[rf][cf][i] + bd1v[cf][i], 0.f);               \
        const int byt = ((row * 1024 + (cb + cf * 16 + g * 4) * 2) ^ ((row & 7) << 4)); \
        *(bf16x4*)(hb + byt) = hv;                                                 \
      }                                                                            \
    }                                                                              \
    barrier_lds_only();                                                            \
    f32x4 acc2[2] = {};                                                            \
    _Pragma("unroll") for (int kf2 = 0; kf2 < 16; ++kf2) {                         \
      _Pragma("unroll") for (int rf2 = 0; rf2 < 2; ++rf2) {                        \
        const int row = rf2 * 16 + q;                                              \
        bf16x8 a = *(const bf16x8*)(hb + ((row * 1024 + kf2 * 64 + g * 16) ^ ((row & 7) << 4))); \
        acc2[rf2] = __builtin_amdgcn_mfma_f32_16x16x32_bf16(bw2[kf2], a, acc2[rf2], 0, 0, 0); \
      }                                                                            \
    }                                                                              \
    const int e = (tile0 + (T)) >> 1;                                              \
    _Pragma("unroll") for (int rf2 = 0; rf2 < 2; ++rf2) {                          \
      float partial = 0.f;                                                         \
      _Pragma("unroll") for (int i = 0; i < 4; ++i) {                              \
        const float xv = mp[e * 128 + wid * 16 + g * 4 + i];                       \
        const float d = xv - (acc2[rf2][i] + bd2v[i]);                             \
        partial += d * d;                                                          \
      }                                                                            \
      partial += __shfl_xor(partial, 16);                                          \
      partial += __shfl_xor(partial, 32);                                          \
      if (lid < 16) s_part[rf2 * 16 + lid][wid] = partial;                         \
    }                                                                              \
    barrier_lds_only();                                                            \
    if (tid < 32) {                                                                \
      float t2 = 0.f;                                                              \
      _Pragma("unroll") for (int w = 0; w < 8; ++w) t2 += s_part[tid][w];          \
      local += (-0.5f * t2 - 0.5f * 128.f * LOG_2PI) * (1.f / 64.f);               \
    }                                                                              \
    barrier_lds_only();                                                            \
  } while (0)

#pragma unroll 1
  for (int t = 0; t < 8; t += 2) {
    DBODY(t, 0, rA0, rA1);
    DBODY(t + 1, 1, rB0, rB1);
  }
#undef DBODY

  if (wid == 0) {
#pragma unroll
    for (int m = 16; m >= 1; m >>= 1) local += __shfl_xor(local, m);
    if (lid == 0) atomicAdd(recon_acc, local);
  }
}

// ---------------- finalize --------------------------------------------------
__global__ void finalize_kernel(const float* __restrict__ accs, float* __restrict__ out) {
  // accs: [0]=integral, [1]=log_intensity_sum, [2]=recon, [3]=sum(z_traj^2)
  const float kl = 0.01f * (accs[3] / 67108864.f);  // 8192*64*128
  const float elbo = accs[1] - accs[0] + accs[2] - kl;
  out[0] = -elbo;
}

extern "C" void kernel_launch(void* const* d_in, const int* in_sizes, int n_in,
                              void* d_out, int out_size, void* d_ws, size_t ws_size,
                              hipStream_t stream) {
  const float* event_marks = (const float*)d_in[0];
  const float* z_events = (const float*)d_in[1];
  const float* z_traj = (const float*)d_in[2];
  const float* times = (const float*)d_in[3];
  const float* Wp = (const float*)d_in[4];
  const float* bp = (const float*)d_in[5];
  const float* W1 = (const float*)d_in[6];
  const float* b1 = (const float*)d_in[7];
  const float* W2 = (const float*)d_in[8];
  const float* b2 = (const float*)d_in[9];
  const float* base_i = (const float*)d_in[10];
  const float* Wd1 = (const float*)d_in[11];
  const float* bd1 = (const float*)d_in[12];
  const float* Wd2 = (const float*)d_in[13];
  const float* bd2 = (const float*)d_in[14];

  float* mp = (float*)d_ws;                              // 1024*128 f32
  float* accs = (float*)((char*)d_ws + 1024 * 128 * 4);  // accumulators

  prep_kernel<<<1025, 128, 0, stream>>>(event_marks, Wp, bp, mp, accs);
  intensity15_kernel<<<256, 768, 0, stream>>>(z_traj, z_events, W1, b1, W2, b2,
                                              base_i, times, accs);
  decoder2_kernel<<<256, 512, 0, stream>>>(z_events, Wd1, bd1, Wd2, bd2, mp,
                                           &accs[2]);
  finalize_kernel<<<1, 1, 0, stream>>>(accs, (float*)d_out);
}